// Round 8
// baseline (140.812 us; speedup 1.0000x reference)
//
#include <hip/hip_runtime.h>
#include <stdint.h>

typedef __attribute__((ext_vector_type(8))) short bf16x8;
typedef __attribute__((ext_vector_type(4))) float f32x4;
typedef unsigned short ushort_t;

#define B_ 8
#define S_ 2048
#define D_ 2048
#define E_ 8
#define J_ 128
#define AR_ 160   // Abf rows allocated: 128 lora_A + 8 gw + pad(zeroed through 159)

static __device__ __forceinline__ unsigned short f2bf(float f) {
  union { float f; uint32_t u; } v; v.f = f;
  uint32_t u = v.u;
  return (unsigned short)((u + 0x7FFFu + ((u >> 16) & 1u)) >> 16);
}
static __device__ __forceinline__ float bf2f(ushort_t h) {
  union { uint32_t u; float f; } v; v.u = ((uint32_t)h) << 16;
  return v.f;
}
// HW packed convert: dst = {hi=bf16(b), lo=bf16(a)} (RNE)
static __device__ __forceinline__ uint32_t pkbf(float a, float b) {
  uint32_t r;
  asm("v_cvt_pk_bf16_f32 %0, %1, %2" : "=v"(r) : "v"(a), "v"(b));
  return r;
}

// K0: Abf[row][d] bf16 row-major, rows = [lora_A(128); gw(8); zeros(..159)].
// Bg[d][j] = bf16(lora_B[e][d][r]), j = e*16+r.
__global__ void k_prep(const float* __restrict__ lA, const float* __restrict__ lB,
                       const float* __restrict__ gw,
                       ushort_t* __restrict__ Abf, ushort_t* __restrict__ Bg) {
  int gid = blockIdx.x * blockDim.x + threadIdx.x;
  int stride = gridDim.x * blockDim.x;
  for (int o = gid; o < AR_ * 256; o += stride) {   // 16B chunks, 256 per row
    int row = o >> 8, c = o & 255;
    int d = c * 8;
    bf16x8 outv = {};
    if (row < 136) {
      const float* src = (row < 128) ? (lA + (size_t)row * D_ + d)
                                     : (gw + (size_t)(row - 128) * D_ + d);
      float4 v0 = *(const float4*)src;
      float4 v1 = *(const float4*)(src + 4);
      outv[0] = (short)f2bf(v0.x); outv[1] = (short)f2bf(v0.y);
      outv[2] = (short)f2bf(v0.z); outv[3] = (short)f2bf(v0.w);
      outv[4] = (short)f2bf(v1.x); outv[5] = (short)f2bf(v1.y);
      outv[6] = (short)f2bf(v1.z); outv[7] = (short)f2bf(v1.w);
    }
    *(bf16x8*)&Abf[(size_t)o * 8] = outv;
  }
  for (int o4 = gid; o4 < (D_ * J_) / 4; o4 += stride) {
    int j4 = o4 & 31, dd = o4 >> 5;
    int e = j4 >> 2, r0 = (j4 & 3) * 4;
    float4 v = *(const float4*)(lB + ((size_t)e * D_ + dd) * 16 + r0);
    uint2 pk;
    pk.x = (uint32_t)f2bf(v.x) | ((uint32_t)f2bf(v.y) << 16);
    pk.y = (uint32_t)f2bf(v.z) | ((uint32_t)f2bf(v.w) << 16);
    ((uint2*)Bg)[o4] = pk;
  }
}

// K1: midb[b][s][j] (bf16) = x . A^T via MFMA. NO LDS, NO barriers: x global->reg
// (double-buffered), A-fragments direct from L1/L2-resident Abf. Wave w owns
// j-tiles w and w+4 over all 32 s-rows; wave 3 also computes the gw tile whose
// row-sums are the router logits (deterministic shuffle reduce, no atomics).
__global__ __launch_bounds__(256) void k_mid(const float* __restrict__ x,
    const ushort_t* __restrict__ Abf, ushort_t* __restrict__ midb,
    float* __restrict__ lpart) {
  const int tid = threadIdx.x;
  const int w = tid >> 6, lane = tid & 63;
  const int lm = lane & 15, g = lane >> 4;
  const int b = blockIdx.y, s0 = blockIdx.x * 32;
  const float* xrow = x + ((size_t)(b * S_ + s0 + lm)) * D_ + g * 8;
  const ushort_t* a0b = Abf + ((size_t)(w * 16 + lm)) * D_ + g * 8;
  const ushort_t* a1b = Abf + ((size_t)((w + 4) * 16 + lm)) * D_ + g * 8;
  const ushort_t* a2b = Abf + ((size_t)(128 + lm)) * D_ + g * 8;

  f32x4 acc0[2] = {}, acc1[2] = {}, acc2[2] = {};

  auto loadX = [&](float4* xr, int t) {
    const float* p0 = xrow + t * 64;
    const float* p1 = p0 + 16 * D_;
    xr[0] = *(const float4*)(p0);
    xr[1] = *(const float4*)(p0 + 4);
    xr[2] = *(const float4*)(p0 + 32);
    xr[3] = *(const float4*)(p0 + 36);
    xr[4] = *(const float4*)(p1);
    xr[5] = *(const float4*)(p1 + 4);
    xr[6] = *(const float4*)(p1 + 32);
    xr[7] = *(const float4*)(p1 + 36);
  };
  auto computeTile = [&](int t, const float4* xr) {
    union U { bf16x8 v; uint32_t u[4]; };
    bf16x8 xf[2][2];
#pragma unroll
    for (int sh = 0; sh < 2; ++sh)
#pragma unroll
      for (int ks = 0; ks < 2; ++ks) {
        float4 v0 = xr[sh * 4 + ks * 2];
        float4 v1 = xr[sh * 4 + ks * 2 + 1];
        U uu;
        uu.u[0] = pkbf(v0.x, v0.y);
        uu.u[1] = pkbf(v0.z, v0.w);
        uu.u[2] = pkbf(v1.x, v1.y);
        uu.u[3] = pkbf(v1.z, v1.w);
        xf[sh][ks] = uu.v;
      }
#pragma unroll
    for (int ks = 0; ks < 2; ++ks) {
      const int dk = t * 64 + ks * 32;
      bf16x8 a0 = *(const bf16x8*)(a0b + dk);
      bf16x8 a1 = *(const bf16x8*)(a1b + dk);
#pragma unroll
      for (int sh = 0; sh < 2; ++sh) {
        acc0[sh] = __builtin_amdgcn_mfma_f32_16x16x32_bf16(a0, xf[sh][ks], acc0[sh], 0, 0, 0);
        acc1[sh] = __builtin_amdgcn_mfma_f32_16x16x32_bf16(a1, xf[sh][ks], acc1[sh], 0, 0, 0);
      }
      if (w == 3) {   // gw tile: rows 128-143 of Abf (136+ are zeros)
        bf16x8 a2 = *(const bf16x8*)(a2b + dk);
#pragma unroll
        for (int sh = 0; sh < 2; ++sh)
          acc2[sh] = __builtin_amdgcn_mfma_f32_16x16x32_bf16(a2, xf[sh][ks], acc2[sh], 0, 0, 0);
      }
    }
  };

  float4 xA[8], xB[8];
  loadX(xA, 0);
#pragma unroll 1
  for (int tt = 0; tt < 16; ++tt) {
    const int t0 = 2 * tt;
    if (t0 + 1 < 32) loadX(xB, t0 + 1);
    computeTile(t0, xA);
    if (t0 + 2 < 32) loadX(xA, t0 + 2);
    computeTile(t0 + 1, xB);
  }

  // mid store: bf16, 8B per lane along j (C rows = j, cols = s)
#pragma unroll
  for (int sh = 0; sh < 2; ++sh) {
    ushort_t* mp = midb + ((size_t)(b * S_ + s0 + sh * 16 + lm)) * J_;
    uint2 pk0, pk1;
    pk0.x = (uint32_t)f2bf(acc0[sh][0]) | ((uint32_t)f2bf(acc0[sh][1]) << 16);
    pk0.y = (uint32_t)f2bf(acc0[sh][2]) | ((uint32_t)f2bf(acc0[sh][3]) << 16);
    pk1.x = (uint32_t)f2bf(acc1[sh][0]) | ((uint32_t)f2bf(acc1[sh][1]) << 16);
    pk1.y = (uint32_t)f2bf(acc1[sh][2]) | ((uint32_t)f2bf(acc1[sh][3]) << 16);
    *(uint2*)&mp[w * 16 + g * 4] = pk0;
    *(uint2*)&mp[(w + 4) * 16 + g * 4] = pk1;
  }

  // logits: wave 3's gw-tile acc; rows g*4+q = experts (g<2), cols = s (lm)
  if (w == 3) {
    float lsum[4];
#pragma unroll
    for (int q = 0; q < 4; ++q) {
      float v = acc2[0][q] + acc2[1][q];
      v += __shfl_xor(v, 1); v += __shfl_xor(v, 2);
      v += __shfl_xor(v, 4); v += __shfl_xor(v, 8);
      lsum[q] = v;
    }
    if (lm == 0 && g < 2) {
      float* lp = lpart + ((size_t)(b * 64 + blockIdx.x)) * 8 + g * 4;
      lp[0] = lsum[0]; lp[1] = lsum[1]; lp[2] = lsum[2]; lp[3] = lsum[3];
    }
  }
}

// K1.5: deterministic router. Fixed-order sum of the 64 per-block partials,
// + biases, top-2, softmax -> rinfo[b] = {i1, i2, w1, w2}.
__global__ void k_router(const float* __restrict__ lpart,
                         const float* __restrict__ tb, const float* __restrict__ mb,
                         const int* __restrict__ task_p, const int* __restrict__ mode_p,
                         float* __restrict__ rinfo) {
  __shared__ float lg[64];
  const int t = threadIdx.x;           // 64 threads
  const int b = t >> 3, e = t & 7;
  float s = 0.f;
  for (int k = 0; k < 64; ++k) s += lpart[((size_t)(b * 64 + k)) * 8 + e];
  lg[t] = s * (1.f / (float)S_) + tb[task_p[0] * E_ + e] + mb[mode_p[0] * E_ + e];
  __syncthreads();
  if (t < B_) {
    float v[8];
#pragma unroll
    for (int e2 = 0; e2 < 8; ++e2) v[e2] = lg[t * 8 + e2];
    int i1 = 0;
#pragma unroll
    for (int e2 = 1; e2 < 8; ++e2) if (v[e2] > v[i1]) i1 = e2;
    int i2 = (i1 == 0) ? 1 : 0;
#pragma unroll
    for (int e2 = 0; e2 < 8; ++e2) if (e2 != i1 && v[e2] > v[i2]) i2 = e2;
    float ex = __expf(v[i2] - v[i1]);
    float w1 = 1.f / (1.f + ex), w2 = ex * w1;
    float4 r;
    r.x = (float)i1; r.y = (float)i2; r.z = w1; r.w = w2;
    ((float4*)rinfo)[t] = r;
  }
}

// K2: out[b][s][d] = sum over 2 active experts (K=32) of mid_bf16 * (coeff*B).
__global__ __launch_bounds__(256) void k_comb(const ushort_t* __restrict__ midb,
    const float* __restrict__ rinfo, const ushort_t* __restrict__ Bg,
    float* __restrict__ out) {
  __shared__ ushort_t Bt[128][40];   // [d-row][2 experts x 16 j], +8 pad
  const int n = blockIdx.x, m = blockIdx.y, b = blockIdx.z;
  const int tid = threadIdx.x, w = tid >> 6, lane = tid & 63;
  const int lm = lane & 15, g = lane >> 4;

  const float4 ri = ((const float4*)rinfo)[b];
  const int i1 = (int)ri.x, i2 = (int)ri.y;
  const float w1 = ri.z, w2 = ri.w;

  // stage active-expert B slice, scaled by combine weight
#pragma unroll
  for (int c = 0; c < 2; ++c) {
    int ci = c * 256 + tid;
    int d = ci >> 2, sub = ci & 3;
    int e = (sub & 2) ? i2 : i1;
    float sc = (sub & 2) ? w2 : w1;
    bf16x8 bv = *(const bf16x8*)(Bg + ((size_t)(n * 128 + d)) * J_ + e * 16 + (sub & 1) * 8);
    bf16x8 bw;
#pragma unroll
    for (int i = 0; i < 8; ++i) bw[i] = (short)f2bf(bf2f((ushort_t)bv[i]) * sc);
    *(bf16x8*)&Bt[d][sub * 8] = bw;
  }

  // P fragment: raw bf16 mid loads of the active 32 j-columns
  const int srow = m * 64 + w * 16 + lm;
  const int jw = (g < 2) ? (i1 * 16 + g * 8) : (i2 * 16 + (g - 2) * 8);
  bf16x8 pf = *(const bf16x8*)&midb[((size_t)(b * S_ + srow)) * J_ + jw];
  __syncthreads();

  f32x4 acc[8] = {};
#pragma unroll
  for (int nn = 0; nn < 8; ++nn) {
    bf16x8 af = *(const bf16x8*)&Bt[nn * 16 + lm][g * 8];
    acc[nn] = __builtin_amdgcn_mfma_f32_16x16x32_bf16(af, pf, acc[nn], 0, 0, 0);
  }

  float* op = out + ((size_t)(b * S_ + srow)) * D_ + n * 128;
#pragma unroll
  for (int nn = 0; nn < 8; ++nn)
    *(f32x4*)&op[nn * 16 + g * 4] = acc[nn];
}

extern "C" void kernel_launch(void* const* d_in, const int* in_sizes, int n_in,
                              void* d_out, int out_size, void* d_ws, size_t ws_size,
                              hipStream_t stream) {
  const float* x    = (const float*)d_in[0];
  const float* gw   = (const float*)d_in[1];
  const float* tb   = (const float*)d_in[2];
  const float* mb   = (const float*)d_in[3];
  const float* lA   = (const float*)d_in[4];
  const float* lB   = (const float*)d_in[5];
  const int* task_p = (const int*)d_in[6];
  const int* mode_p = (const int*)d_in[7];
  float* out = (float*)d_out;
  char* ws = (char*)d_ws;
  ushort_t* midb = (ushort_t*)ws;                  // 4,194,304 B
  ushort_t* Abf  = (ushort_t*)(ws + 4194304);      //   655,360 B
  ushort_t* Bg   = (ushort_t*)(ws + 4849664);      //   524,288 B
  float* lpart   = (float*)(ws + 5373952);         //    16,384 B
  float* rinfo   = (float*)(ws + 5390336);         //       128 B

  hipLaunchKernelGGL(k_prep, dim3(256), dim3(256), 0, stream, lA, lB, gw, Abf, Bg);
  hipLaunchKernelGGL(k_mid, dim3(64, 8), dim3(256), 0, stream, x, Abf, midb, lpart);
  hipLaunchKernelGGL(k_router, dim3(1), dim3(64), 0, stream,
                     lpart, tb, mb, task_p, mode_p, rinfo);
  hipLaunchKernelGGL(k_comb, dim3(16, 32, 8), dim3(256), 0, stream, midb, rinfo, Bg, out);
}

// Round 9
// 85.260 us; speedup vs baseline: 1.6516x; 1.6516x over previous
//
#include <hip/hip_runtime.h>
#include <stdint.h>

typedef __attribute__((ext_vector_type(8))) short bf16x8;
typedef __attribute__((ext_vector_type(4))) float f32x4;
typedef __attribute__((ext_vector_type(16))) float f32x16;
typedef unsigned short ushort_t;

#define B_ 8
#define S_ 2048
#define D_ 2048
#define E_ 8
#define J_ 128
#define AROWS 160             // 128 lora_A + 8 gw + 24 zero pad (5 j32-tiles)
#define ATILE (AROWS * 64)    // shorts per k64-tile = 10240 (20 KB)

static __device__ __forceinline__ unsigned short f2bf(float f) {
  union { float f; uint32_t u; } v; v.f = f;
  uint32_t u = v.u;
  return (unsigned short)((u + 0x7FFFu + ((u >> 16) & 1u)) >> 16);
}
static __device__ __forceinline__ float bf2f(ushort_t h) {
  union { uint32_t u; float f; } v; v.u = ((uint32_t)h) << 16;
  return v.f;
}
// HW packed convert: dst = {lo=bf16(a), hi=bf16(b)} (RNE)
static __device__ __forceinline__ uint32_t pkbf(float a, float b) {
  uint32_t r;
  asm("v_cvt_pk_bf16_f32 %0, %1, %2" : "=v"(r) : "v"(a), "v"(b));
  return r;
}

#define GLL16(gsrc, ldst)                                                        \
  __builtin_amdgcn_global_load_lds(                                              \
      (const __attribute__((address_space(1))) void*)(gsrc),                     \
      (__attribute__((address_space(3))) void*)(ldst), 16, 0, 0)

// counted-vmcnt barrier: drain all but newest N vmem ops; drain ds ops; barrier.
#define VMBAR(N)                                                                 \
  do {                                                                           \
    asm volatile("s_waitcnt vmcnt(" #N ") lgkmcnt(0)\n\ts_barrier" ::: "memory");\
    __builtin_amdgcn_sched_barrier(0);                                           \
  } while (0)

// K0: AgE[kt][row 0..159][c 0..7][8]: chunk-swizzled bf16 A_ext; storage chunk c
// of row holds logical chunk c^(row&7). Rows: 0-127 lora_A, 128-135 gw, rest 0.
// Bg[d][j] = bf16(lora_B[e][d][r]), j = e*16+r.
__global__ void k_prep(const float* __restrict__ lA, const float* __restrict__ lB,
                       const float* __restrict__ gw,
                       ushort_t* __restrict__ AgE, ushort_t* __restrict__ Bg) {
  int gid = blockIdx.x * blockDim.x + threadIdx.x;
  int stride = gridDim.x * blockDim.x;
  for (int o = gid; o < 32 * AROWS * 8; o += stride) {   // 16B chunks
    int kt = o / (AROWS * 8);
    int rem = o - kt * (AROWS * 8);
    int row = rem >> 3, c = rem & 7;
    int d = kt * 64 + (((c ^ row) & 7) << 3);
    bf16x8 outv = {};
    if (row < 136) {
      const float* src = (row < 128) ? (lA + (size_t)row * D_ + d)
                                     : (gw + (size_t)(row - 128) * D_ + d);
      float4 v0 = *(const float4*)src;
      float4 v1 = *(const float4*)(src + 4);
      outv[0] = (short)f2bf(v0.x); outv[1] = (short)f2bf(v0.y);
      outv[2] = (short)f2bf(v0.z); outv[3] = (short)f2bf(v0.w);
      outv[4] = (short)f2bf(v1.x); outv[5] = (short)f2bf(v1.y);
      outv[6] = (short)f2bf(v1.z); outv[7] = (short)f2bf(v1.w);
    }
    *(bf16x8*)&AgE[(size_t)o * 8] = outv;
  }
  for (int o4 = gid; o4 < (D_ * J_) / 4; o4 += stride) {
    int j4 = o4 & 31, dd = o4 >> 5;
    int e = j4 >> 2, r0 = (j4 & 3) * 4;
    float4 v = *(const float4*)(lB + ((size_t)e * D_ + dd) * 16 + r0);
    uint2 pk;
    pk.x = (uint32_t)f2bf(v.x) | ((uint32_t)f2bf(v.y) << 16);
    pk.y = (uint32_t)f2bf(v.z) | ((uint32_t)f2bf(v.w) << 16);
    ((uint2*)Bg)[o4] = pk;
  }
}

// K1: midb[b][s][j] (bf16) = x . A^T via 32x32x16 MFMA. x: coalesced fp32
// reg-load -> cvt_pk bf16 -> swizzled LDS. A: gload_lds double-buffered.
// One counted-vmcnt barrier per k64-tile. Wave w owns j32-tile w; wave 3 also
// the gw tile (rows 128-159) whose row-sums are the logits (deterministic).
__global__ __launch_bounds__(256) void k_mid(const float* __restrict__ x,
    const ushort_t* __restrict__ AgE, ushort_t* __restrict__ midb,
    float* __restrict__ lpart) {
  __shared__ ushort_t Ab[2][ATILE];   // 2 x 20 KB
  __shared__ ushort_t Xb[2][2048];    // 2 x 4 KB: 32 rows x 8 chunks, swizzled
  const int tid = threadIdx.x;
  const int w = tid >> 6, lane = tid & 63;
  const int l31 = lane & 31, hi = lane >> 5;
  const int b = blockIdx.y, s0 = blockIdx.x * 32;
  const float* xb = x + ((size_t)(b * S_ + s0)) * D_;
  // x stage mapping: thread covers rows (tid>>4), 16+(tid>>4), cols (tid&15)*4
  const int xr = tid >> 4, xc = (tid & 15) * 4;
  const float* xsrc0 = xb + (size_t)xr * D_ + xc;
  const float* xsrc1 = xb + (size_t)(16 + xr) * D_ + xc;
  const int xw0 = xr * 64 + ((((xc >> 3) ^ (xr & 7))) << 3) + ((xc >> 2) & 1) * 4;
  const int xw1 = (16 + xr) * 64 + ((((xc >> 3) ^ ((16 + xr) & 7))) << 3) + ((xc >> 2) & 1) * 4;

  f32x16 acc = {};
  f32x16 acc2 = {};

  auto stageA = [&](int buf, int kt) {
#pragma unroll
    for (int c = 0; c < 5; ++c) {
      int ch = c * 256 + tid;
      const ushort_t* src = AgE + (size_t)kt * ATILE + (size_t)ch * 8;
      GLL16(src, &Ab[buf][ch * 8]);
    }
  };
  auto loadX = [&](float4* xr4, int t) {
    xr4[0] = *(const float4*)(xsrc0 + t * 64);
    xr4[1] = *(const float4*)(xsrc1 + t * 64);
  };
  auto cvtWrite = [&](int buf, const float4* xr4) {
    uint2 p0, p1;
    p0.x = pkbf(xr4[0].x, xr4[0].y); p0.y = pkbf(xr4[0].z, xr4[0].w);
    p1.x = pkbf(xr4[1].x, xr4[1].y); p1.y = pkbf(xr4[1].z, xr4[1].w);
    *(uint2*)&Xb[buf][xw0] = p0;
    *(uint2*)&Xb[buf][xw1] = p1;
  };
  auto computeTile = [&](int t) {
    const int cb = t & 1;
#pragma unroll
    for (int ks = 0; ks < 4; ++ks) {
      const int cc = ks * 2 + hi;
      bf16x8 xf = *(const bf16x8*)&Xb[cb][l31 * 64 + ((cc ^ (l31 & 7)) << 3)];
      const int arow = w * 32 + l31;
      bf16x8 af = *(const bf16x8*)&Ab[cb][arow * 64 + ((cc ^ (l31 & 7)) << 3)];
      acc = __builtin_amdgcn_mfma_f32_32x32x16_bf16(af, xf, acc, 0, 0, 0);
      if (w == 3) {
        const int arow2 = 128 + l31;
        bf16x8 af2 = *(const bf16x8*)&Ab[cb][arow2 * 64 + ((cc ^ (l31 & 7)) << 3)];
        acc2 = __builtin_amdgcn_mfma_f32_32x32x16_bf16(af2, xf, acc2, 0, 0, 0);
      }
    }
  };

  float4 xA[2], xB[2];
  // prologue: A(0) DMA; x0 -> regs -> LDS buf0; x1 -> regs
  stageA(0, 0);
  __builtin_amdgcn_sched_barrier(0);
  loadX(xA, 0);
  cvtWrite(0, xA);
  loadX(xB, 1);
  __builtin_amdgcn_sched_barrier(0);

  // body(t): VMBAR; stage A(t+1); write x(t+1); load x(t+2); compute(t)
#pragma unroll 1
  for (int tt = 0; tt < 15; ++tt) {
    const int t = 2 * tt;
    VMBAR(2);                       // drain A(t); keep x(t+1):2
    stageA((t + 1) & 1, t + 1);
    cvtWrite((t + 1) & 1, xB);      // x(t+1), loaded one body ago
    loadX(xA, t + 2);
    computeTile(t);
    VMBAR(2);                       // drain A(t+1); keep x(t+2):2
    stageA(t & 1, t + 2);
    cvtWrite(t & 1, xA);            // x(t+2)
    loadX(xB, t + 3);
    computeTile(t + 1);
  }
  // t = 30
  VMBAR(2);
  stageA(1, 31);
  cvtWrite(1, xB);                  // x(31)
  computeTile(30);
  // t = 31
  VMBAR(0);
  computeTile(31);

  // midb store: C layout col(s)=l31, row(j)=(q&3)+8*(q>>2)+4*hi.
  // For q-group G: 4 consecutive j at j0 = w*32 + G*8 + 4*hi.
  {
    ushort_t* mp = midb + ((size_t)(b * S_ + s0 + l31)) * J_ + w * 32 + 4 * hi;
#pragma unroll
    for (int G = 0; G < 4; ++G) {
      uint2 pk;
      pk.x = pkbf(acc[G * 4 + 0], acc[G * 4 + 1]);
      pk.y = pkbf(acc[G * 4 + 2], acc[G * 4 + 3]);
      *(uint2*)&mp[G * 8] = pk;
    }
  }

  // logits: wave 3's gw tile; experts = tile rows 0-7 = q + 4*hi for q<4.
  if (w == 3) {
    float lsq[4];
#pragma unroll
    for (int q = 0; q < 4; ++q) {
      float v = acc2[q];
      v += __shfl_xor(v, 1); v += __shfl_xor(v, 2);
      v += __shfl_xor(v, 4); v += __shfl_xor(v, 8);
      v += __shfl_xor(v, 16);
      lsq[q] = v;
    }
    if (l31 == 0) {
      float* lp = lpart + ((size_t)(b * 64 + blockIdx.x)) * 8 + hi * 4;
      lp[0] = lsq[0]; lp[1] = lsq[1]; lp[2] = lsq[2]; lp[3] = lsq[3];
    }
  }
}

// K1.5: deterministic router. Fixed-order sum of the 64 per-block partials,
// + biases, top-2, softmax -> rinfo[b] = {i1, i2, w1, w2}.
__global__ void k_router(const float* __restrict__ lpart,
                         const float* __restrict__ tb, const float* __restrict__ mb,
                         const int* __restrict__ task_p, const int* __restrict__ mode_p,
                         float* __restrict__ rinfo) {
  __shared__ float lg[64];
  const int t = threadIdx.x;           // 64 threads
  const int b = t >> 3, e = t & 7;
  float s = 0.f;
  for (int k = 0; k < 64; ++k) s += lpart[((size_t)(b * 64 + k)) * 8 + e];
  lg[t] = s * (1.f / (float)S_) + tb[task_p[0] * E_ + e] + mb[mode_p[0] * E_ + e];
  __syncthreads();
  if (t < B_) {
    float v[8];
#pragma unroll
    for (int e2 = 0; e2 < 8; ++e2) v[e2] = lg[t * 8 + e2];
    int i1 = 0;
#pragma unroll
    for (int e2 = 1; e2 < 8; ++e2) if (v[e2] > v[i1]) i1 = e2;
    int i2 = (i1 == 0) ? 1 : 0;
#pragma unroll
    for (int e2 = 0; e2 < 8; ++e2) if (e2 != i1 && v[e2] > v[i2]) i2 = e2;
    float ex = __expf(v[i2] - v[i1]);
    float w1 = 1.f / (1.f + ex), w2 = ex * w1;
    float4 r;
    r.x = (float)i1; r.y = (float)i2; r.z = w1; r.w = w2;
    ((float4*)rinfo)[t] = r;
  }
}

// K2: out[b][s][d] = sum over 2 active experts (K=32) of mid_bf16 * (coeff*B).
__global__ __launch_bounds__(256) void k_comb(const ushort_t* __restrict__ midb,
    const float* __restrict__ rinfo, const ushort_t* __restrict__ Bg,
    float* __restrict__ out) {
  __shared__ ushort_t Bt[128][40];   // [d-row][2 experts x 16 j], +8 pad
  const int n = blockIdx.x, m = blockIdx.y, b = blockIdx.z;
  const int tid = threadIdx.x, w = tid >> 6, lane = tid & 63;
  const int lm = lane & 15, g = lane >> 4;

  const float4 ri = ((const float4*)rinfo)[b];
  const int i1 = (int)ri.x, i2 = (int)ri.y;
  const float w1 = ri.z, w2 = ri.w;

  // stage active-expert B slice, scaled by combine weight
#pragma unroll
  for (int c = 0; c < 2; ++c) {
    int ci = c * 256 + tid;
    int d = ci >> 2, sub = ci & 3;
    int e = (sub & 2) ? i2 : i1;
    float sc = (sub & 2) ? w2 : w1;
    bf16x8 bv = *(const bf16x8*)(Bg + ((size_t)(n * 128 + d)) * J_ + e * 16 + (sub & 1) * 8);
    bf16x8 bw;
#pragma unroll
    for (int i = 0; i < 8; ++i) bw[i] = (short)f2bf(bf2f((ushort_t)bv[i]) * sc);
    *(bf16x8*)&Bt[d][sub * 8] = bw;
  }

  // P fragment: raw bf16 mid loads of the active 32 j-columns
  const int srow = m * 64 + w * 16 + lm;
  const int jw = (g < 2) ? (i1 * 16 + g * 8) : (i2 * 16 + (g - 2) * 8);
  bf16x8 pf = *(const bf16x8*)&midb[((size_t)(b * S_ + srow)) * J_ + jw];
  __syncthreads();

  f32x4 acc[8] = {};
#pragma unroll
  for (int nn = 0; nn < 8; ++nn) {
    bf16x8 af = *(const bf16x8*)&Bt[nn * 16 + lm][g * 8];
    acc[nn] = __builtin_amdgcn_mfma_f32_16x16x32_bf16(af, pf, acc[nn], 0, 0, 0);
  }

  float* op = out + ((size_t)(b * S_ + srow)) * D_ + n * 128;
#pragma unroll
  for (int nn = 0; nn < 8; ++nn)
    *(f32x4*)&op[nn * 16 + g * 4] = acc[nn];
}

extern "C" void kernel_launch(void* const* d_in, const int* in_sizes, int n_in,
                              void* d_out, int out_size, void* d_ws, size_t ws_size,
                              hipStream_t stream) {
  const float* x    = (const float*)d_in[0];
  const float* gw   = (const float*)d_in[1];
  const float* tb   = (const float*)d_in[2];
  const float* mb   = (const float*)d_in[3];
  const float* lA   = (const float*)d_in[4];
  const float* lB   = (const float*)d_in[5];
  const int* task_p = (const int*)d_in[6];
  const int* mode_p = (const int*)d_in[7];
  float* out = (float*)d_out;
  char* ws = (char*)d_ws;
  ushort_t* midb = (ushort_t*)ws;                  // 4,194,304 B
  ushort_t* AgE  = (ushort_t*)(ws + 4194304);      //   655,360 B
  ushort_t* Bg   = (ushort_t*)(ws + 4849664);      //   524,288 B
  float* lpart   = (float*)(ws + 5373952);         //    16,384 B
  float* rinfo   = (float*)(ws + 5390336);         //       128 B

  hipLaunchKernelGGL(k_prep, dim3(256), dim3(256), 0, stream, lA, lB, gw, AgE, Bg);
  hipLaunchKernelGGL(k_mid, dim3(64, 8), dim3(256), 0, stream, x, AgE, midb, lpart);
  hipLaunchKernelGGL(k_router, dim3(1), dim3(64), 0, stream,
                     lpart, tb, mb, task_p, mode_p, rinfo);
  hipLaunchKernelGGL(k_comb, dim3(16, 32, 8), dim3(256), 0, stream, midb, rinfo, Bg, out);
}